// Round 1
// baseline (1117.283 us; speedup 1.0000x reference)
//
#include <hip/hip_runtime.h>
#include <math.h>

#define Bn 4
#define Cn 32
#define Dn 64
#define Hn 64
#define Wn 64
#define PLANE (Hn * Wn)   // 4096
#define DT 8              // d-planes per block
#define LW 66             // padded plane row (64 + 2 halo)

__device__ __forceinline__ float gelu_exact(float x) {
    return 0.5f * x * (1.0f + erff(x * 0.70710678118654752f));
}

// One step: dst = gelu(src + depthwise_conv3x3x3(src)), zero padding.
// Block: 256 threads, handles (b, c, d0..d0+7) with a rolling 3-plane LDS buffer.
__global__ __launch_bounds__(256, 2)
void EmergentSpatialPropagation_step(const float* __restrict__ src,
                                     const float* __restrict__ wgt,
                                     float* __restrict__ dst) {
    __shared__ float lds[3][LW * LW];

    const int tid = threadIdx.x;
    const int d0  = blockIdx.x * DT;
    const int c   = blockIdx.y;
    const int b   = blockIdx.z;
    const size_t base = ((size_t)(b * Cn + c)) * (size_t)(Dn * PLANE);

    // Zero all of LDS once; halo rows/cols are never written again, stay zero.
    {
        float* p = &lds[0][0];
        for (int i = tid; i < 3 * LW * LW; i += 256) p[i] = 0.0f;
    }

    // Per-channel 27 taps (block-uniform -> scalar loads).
    float wt[27];
#pragma unroll
    for (int k = 0; k < 27; k++) wt[k] = wgt[c * 27 + k];

    // slot(p) = (p+1)%3  (p may be -1)
    auto load_plane = [&](int p) {
        float* pl = lds[(p + 1) % 3];
        if (p >= 0 && p < Dn) {
            const float4* g = (const float4*)(src + base + (size_t)p * PLANE);
#pragma unroll
            for (int i = 0; i < 4; i++) {
                int idx = i * 256 + tid;        // float4 index within plane
                float4 v = g[idx];
                int e = idx * 4;
                int h = e >> 6, w = e & 63;
                float* r = pl + (h + 1) * LW + (w + 1);
                r[0] = v.x; r[1] = v.y; r[2] = v.z; r[3] = v.w;
            }
        } else {
#pragma unroll
            for (int i = 0; i < 4; i++) {
                int e = (i * 256 + tid) * 4;
                int h = e >> 6, w = e & 63;
                float* r = pl + (h + 1) * LW + (w + 1);
                r[0] = 0.f; r[1] = 0.f; r[2] = 0.f; r[3] = 0.f;
            }
        }
    };

    load_plane(d0 - 1);
    load_plane(d0);

    for (int dz = d0; dz < d0 + DT; dz++) {
        load_plane(dz + 1);
        __syncthreads();

        const float* p0 = lds[(dz)     % 3];   // plane dz-1
        const float* p1 = lds[(dz + 1) % 3];   // plane dz
        const float* p2 = lds[(dz + 2) % 3];   // plane dz+1

        float* d = dst + base + (size_t)dz * PLANE;
#pragma unroll 4
        for (int i = 0; i < 16; i++) {
            int idx = i * 256 + tid;
            int h = idx >> 6, w = idx & 63;
            float acc = 0.0f;
#pragma unroll
            for (int ky = 0; ky < 3; ky++) {
#pragma unroll
                for (int kx = 0; kx < 3; kx++) {
                    int off = (h + ky) * LW + (w + kx);
                    acc = fmaf(p0[off], wt[0 + ky * 3 + kx], acc);
                    acc = fmaf(p1[off], wt[9 + ky * 3 + kx], acc);
                    acc = fmaf(p2[off], wt[18 + ky * 3 + kx], acc);
                }
            }
            float xc = p1[(h + 1) * LW + (w + 1)];
            d[idx] = gelu_exact(xc + acc);
        }
        __syncthreads();
    }
}

extern "C" void kernel_launch(void* const* d_in, const int* in_sizes, int n_in,
                              void* d_out, int out_size, void* d_ws, size_t ws_size,
                              hipStream_t stream) {
    const float* x   = (const float*)d_in[0];
    const float* wgt = (const float*)d_in[1];
    float* out = (float*)d_out;
    float* ws  = (float*)d_ws;

    dim3 grid(Dn / DT, Cn, Bn);   // 8 x 32 x 4 = 1024 blocks
    dim3 block(256);

    // 8 steps, ping-pong: in -> ws -> out -> ws -> ... -> out
    const float* src = x;
    for (int s = 0; s < 8; s++) {
        float* dst = (s & 1) ? out : ws;
        EmergentSpatialPropagation_step<<<grid, block, 0, stream>>>(src, wgt, dst);
        src = dst;
    }
}

// Round 2
// 926.233 us; speedup vs baseline: 1.2063x; 1.2063x over previous
//
#include <hip/hip_runtime.h>
#include <math.h>

#define Bn 4
#define Cn 32
#define Dn 64
#define Hn 64
#define Wn 64
#define PLANE (Hn * Wn)    // 4096
#define DT 16              // d-planes per block
#define LSTRIDE 68         // padded row stride (16B-aligned rows: 68*4=272=17*16)
#define LROWS 66           // rows -1..64 -> padded 0..65
#define LPLANE (LROWS * LSTRIDE)   // 4488 floats (17952 B, multiple of 16)

__device__ __forceinline__ float gelu_exact(float x) {
    return 0.5f * x * (1.0f + erff(x * 0.70710678118654752f));
}

// One step: dst = gelu(src + depthwise_conv3x3x3(src)), zero padding.
// Block: 512 threads, (b, c, d0..d0+15), rolling 3-plane LDS buffer.
// Each thread computes 8 consecutive W outputs; LDS reads are b128/b64.
__global__ __launch_bounds__(512, 4)
void EmergentSpatialPropagation_step(const float* __restrict__ src,
                                     const float* __restrict__ wgt,
                                     float* __restrict__ dst) {
    __shared__ float lds[3 * LPLANE];   // 53856 B -> 2 blocks/CU

    const int tid = threadIdx.x;
    const int d0  = blockIdx.x * DT;
    const int c   = blockIdx.y;
    const int b   = blockIdx.z;
    const size_t base = ((size_t)(b * Cn + c)) * (size_t)(Dn * PLANE);

    // Zero all LDS once; halo rows/cols never rewritten, stay zero.
    for (int i = tid; i < 3 * LPLANE; i += 512) lds[i] = 0.0f;
    __syncthreads();

    // Per-channel taps (block-uniform -> scalar loads expected).
    float wt[27];
#pragma unroll
    for (int k = 0; k < 27; k++) wt[k] = wgt[c * 27 + k];

    const int h  = tid >> 3;         // output row 0..63
    const int w0 = (tid & 7) << 3;   // output col group 0,8,..,56

    // slot(p) = (p+1)%3, p may be -1
    auto load_plane = [&](int p) {
        float* pl = &lds[((p + 1) % 3) * LPLANE];
        if ((unsigned)p < (unsigned)Dn) {
            const float4* g = (const float4*)(src + base + (size_t)p * PLANE);
#pragma unroll
            for (int i = 0; i < 2; i++) {
                int idx = i * 512 + tid;          // float4 index in plane
                float4 v = g[idx];
                int e = idx << 2;
                float* r = pl + ((e >> 6) + 1) * LSTRIDE + (e & 63) + 1;
                r[0] = v.x; r[1] = v.y; r[2] = v.z; r[3] = v.w;
            }
        } else {
#pragma unroll
            for (int i = 0; i < 2; i++) {
                int e = (i * 512 + tid) << 2;
                float* r = pl + ((e >> 6) + 1) * LSTRIDE + (e & 63) + 1;
                r[0] = 0.f; r[1] = 0.f; r[2] = 0.f; r[3] = 0.f;
            }
        }
    };

    load_plane(d0 - 1);
    load_plane(d0);

    for (int dz = d0; dz < d0 + DT; dz++) {
        load_plane(dz + 1);
        __syncthreads();

        const float* P0 = &lds[((dz)     % 3) * LPLANE];  // plane dz-1
        const float* P1 = &lds[((dz + 1) % 3) * LPLANE];  // plane dz
        const float* P2 = &lds[((dz + 2) % 3) * LPLANE];  // plane dz+1
        const float* P[3] = {P0, P1, P2};

        float acc[8] = {0, 0, 0, 0, 0, 0, 0, 0};
        float xc[8];

#pragma unroll
        for (int pz = 0; pz < 3; pz++) {
#pragma unroll
            for (int ky = 0; ky < 3; ky++) {
                // taps for output rows: data rows h-1..h+1 = padded rows h..h+2
                const float* r = P[pz] + (h + ky) * LSTRIDE + w0;
                float4 a  = *(const float4*)(r);       // padded cols w0..w0+3
                float4 b4 = *(const float4*)(r + 4);   // w0+4..w0+7
                float2 c2 = *(const float2*)(r + 8);   // w0+8, w0+9
                float f[10] = {a.x, a.y, a.z, a.w, b4.x, b4.y, b4.z, b4.w, c2.x, c2.y};
                const float w0t = wt[pz * 9 + ky * 3 + 0];
                const float w1t = wt[pz * 9 + ky * 3 + 1];
                const float w2t = wt[pz * 9 + ky * 3 + 2];
#pragma unroll
                for (int j = 0; j < 8; j++) {
                    acc[j] = fmaf(f[j],     w0t, acc[j]);
                    acc[j] = fmaf(f[j + 1], w1t, acc[j]);
                    acc[j] = fmaf(f[j + 2], w2t, acc[j]);
                }
                if (pz == 1 && ky == 1) {
#pragma unroll
                    for (int j = 0; j < 8; j++) xc[j] = f[j + 1];
                }
            }
        }

        float* dptr = dst + base + (size_t)dz * PLANE + h * Wn + w0;
#pragma unroll
        for (int j = 0; j < 8; j++) dptr[j] = gelu_exact(xc[j] + acc[j]);

        __syncthreads();   // protect slot reuse before next load_plane
    }
}

extern "C" void kernel_launch(void* const* d_in, const int* in_sizes, int n_in,
                              void* d_out, int out_size, void* d_ws, size_t ws_size,
                              hipStream_t stream) {
    const float* x   = (const float*)d_in[0];
    const float* wgt = (const float*)d_in[1];
    float* out = (float*)d_out;
    float* ws  = (float*)d_ws;

    dim3 grid(Dn / DT, Cn, Bn);   // 4 x 32 x 4 = 512 blocks -> 2/CU resident
    dim3 block(512);

    // 8 steps, ping-pong: in -> ws -> out -> ws -> ... -> out
    const float* src = x;
    for (int s = 0; s < 8; s++) {
        float* dst = (s & 1) ? out : ws;
        EmergentSpatialPropagation_step<<<grid, block, 0, stream>>>(src, wgt, dst);
        src = dst;
    }
}

// Round 3
// 743.509 us; speedup vs baseline: 1.5027x; 1.2458x over previous
//
#include <hip/hip_runtime.h>
#include <math.h>

#define Bn 4
#define Cn 32
#define Dn 64
#define Hn 64
#define Wn 64
#define PLANE (Hn * Wn)    // 4096
#define DT 16              // d-planes per block
#define LSTRIDE 68         // padded row stride: 68*4 = 272 B = 17*16 (rows 16B-aligned)
#define LROWS 66           // padded rows 0..65 hold data rows -1..64
#define LPLANE (LROWS * LSTRIDE)   // 4488 floats = 17952 B (multiple of 16)

// Exact-grade GELU: 0.5x(1+erf(x/sqrt2)) with A&S 7.1.26 erf (max abs err 1.5e-7).
// For s=|x|/sqrt2 >= 0: q = (1 - erf(s)) = P(t)*exp(-s^2), t = 1/(1+0.3275911 s).
// gelu = x>0 ? x - 0.5*x*q : 0.5*x*q.
__device__ __forceinline__ float gelu_exact(float x) {
    float s = fabsf(x) * 0.70710678118654752f;
    float t = __builtin_amdgcn_rcpf(fmaf(0.3275911f, s, 1.0f));
    float P = t * fmaf(t, fmaf(t, fmaf(t, fmaf(t, 1.061405429f, -1.453152027f),
                                       1.421413741f), -0.284496736f), 0.254829592f);
    float E = __builtin_amdgcn_exp2f(-s * s * 1.4426950408889634f);
    float q = P * E;
    float hxq = 0.5f * x * q;
    return x > 0.f ? x - hxq : hxq;
}

__device__ __forceinline__ void read_row(const float* base, float f[10]) {
    float4 a = *(const float4*)(base);       // 16B-aligned
    float4 b = *(const float4*)(base + 4);
    float2 c = *(const float2*)(base + 8);
    f[0] = a.x; f[1] = a.y; f[2] = a.z; f[3] = a.w;
    f[4] = b.x; f[5] = b.y; f[6] = b.z; f[7] = b.w;
    f[8] = c.x; f[9] = c.y;
}

__device__ __forceinline__ void acc_row(const float f[10], float w0t, float w1t,
                                        float w2t, float acc[8]) {
#pragma unroll
    for (int j = 0; j < 8; j++) {
        acc[j] = fmaf(f[j],     w0t, acc[j]);
        acc[j] = fmaf(f[j + 1], w1t, acc[j]);
        acc[j] = fmaf(f[j + 2], w2t, acc[j]);
    }
}

// One step: dst = gelu(src + depthwise_conv3x3x3(src)), zero padding.
// 512 threads, (b, c, d0..d0+15). 4-slot LDS ring, 1 barrier/iter,
// register prefetch of plane dz+2, register row-cache of planes dz, dz+1.
__global__ __launch_bounds__(512, 4)
void EmergentSpatialPropagation_step(const float* __restrict__ src,
                                     const float* __restrict__ wgt,
                                     float* __restrict__ dst) {
    __shared__ float lds[4 * LPLANE];   // 71808 B -> 2 blocks/CU

    const int tid = threadIdx.x;
    const int d0  = blockIdx.x * DT;
    const int c   = blockIdx.y;
    const int b   = blockIdx.z;
    const size_t base = ((size_t)(b * Cn + c)) * (size_t)(Dn * PLANE);

    // Zero all 4 slots once; halo cells are never rewritten, stay zero.
    for (int i = tid; i < 4 * LPLANE; i += 512) lds[i] = 0.0f;

    float wt[27];
#pragma unroll
    for (int k = 0; k < 27; k++) wt[k] = wgt[c * 27 + k];   // block-uniform -> SGPR

    const int h  = tid >> 3;          // output row 0..63
    const int w0 = (tid & 7) << 3;    // output col group
    const int m  = tid & 15;          // staging lane role (512 % 16 == 0)

    auto slot = [&](int p) -> float* { return &lds[((p + 1) & 3) * LPLANE]; };

    // Global plane p -> 2 float4 regs (zeros outside volume).
    auto load_g = [&](int p, float4 G[2]) {
        if ((unsigned)p < (unsigned)Dn) {
            const float4* g = (const float4*)(src + base + (size_t)p * PLANE);
            G[0] = g[tid];
            G[1] = g[512 + tid];
        } else {
            G[0] = make_float4(0.f, 0.f, 0.f, 0.f);
            G[1] = make_float4(0.f, 0.f, 0.f, 0.f);
        }
    };

    // Regs -> LDS slot, 16B-aligned conflict-free writes via shfl repack.
    // Padded group cols 4m..4m+3 hold data cols 4m-1..4m+2 = {prev.w, x, y, z}.
    auto write_plane = [&](int p, const float4 G[2]) {
        float* pl = slot(p);
#pragma unroll
        for (int i = 0; i < 2; i++) {
            int idx = i * 512 + tid;
            int row = (idx >> 4) + 1;                 // padded row 1..64
            float prev = __shfl_up(G[i].w, 1);
            if (m == 0) prev = 0.f;                   // left zero halo
            float4 W = make_float4(prev, G[i].x, G[i].y, G[i].z);
            *(float4*)(pl + row * LSTRIDE + 4 * m) = W;
            if (m == 15) pl[row * LSTRIDE + 64] = G[i].w;   // data col 63
        }
    };

    // ---- Prologue: stage planes d0-1, d0, d0+1 ----
    __syncthreads();   // zeros visible before staging writes
    {
        float4 Ga[2], Gb[2], Gc[2];
        load_g(d0 - 1, Ga); load_g(d0, Gb); load_g(d0 + 1, Gc);
        write_plane(d0 - 1, Ga); write_plane(d0, Gb); write_plane(d0 + 1, Gc);
    }
    __syncthreads();

    // Register row-cache: C0 = plane dz rows, C1 = plane dz+1 rows.
    float C0[3][10], C1[3][10];
#pragma unroll
    for (int ky = 0; ky < 3; ky++)
        read_row(slot(d0) + (h + ky) * LSTRIDE + w0, C0[ky]);

    for (int it = 0; it < DT; it++) {
        const int dz = d0 + it;

        // Prefetch plane dz+2 into regs (hidden behind compute).
        float4 G[2];
        if (it < DT - 1) load_g(dz + 2, G);

        // Fresh rows of plane dz+1 (written iter-1, visible after barrier).
#pragma unroll
        for (int ky = 0; ky < 3; ky++)
            read_row(slot(dz + 1) + (h + ky) * LSTRIDE + w0, C1[ky]);

        float acc[8] = {0, 0, 0, 0, 0, 0, 0, 0};

        // Plane dz-1 (last use): read from LDS, consume immediately.
#pragma unroll
        for (int ky = 0; ky < 3; ky++) {
            float T[10];
            read_row(slot(dz - 1) + (h + ky) * LSTRIDE + w0, T);
            acc_row(T, wt[ky * 3 + 0], wt[ky * 3 + 1], wt[ky * 3 + 2], acc);
        }
        // Plane dz (cached).
#pragma unroll
        for (int ky = 0; ky < 3; ky++)
            acc_row(C0[ky], wt[9 + ky * 3 + 0], wt[9 + ky * 3 + 1], wt[9 + ky * 3 + 2], acc);
        // Plane dz+1 (cached).
#pragma unroll
        for (int ky = 0; ky < 3; ky++)
            acc_row(C1[ky], wt[18 + ky * 3 + 0], wt[18 + ky * 3 + 1], wt[18 + ky * 3 + 2], acc);

        float* dptr = dst + base + (size_t)dz * PLANE + h * Wn + w0;
#pragma unroll
        for (int j = 0; j < 8; j++)
            dptr[j] = gelu_exact(C0[1][j + 1] + acc[j]);   // center = plane dz

        if (it < DT - 1) {
            write_plane(dz + 2, G);   // slot (dz+3)&3: not read this iter
            __syncthreads();          // single barrier per iteration
        }

        // Rotate cache: plane dz+1 becomes next iter's plane dz.
#pragma unroll
        for (int ky = 0; ky < 3; ky++)
#pragma unroll
            for (int k = 0; k < 10; k++) C0[ky][k] = C1[ky][k];
    }
}

extern "C" void kernel_launch(void* const* d_in, const int* in_sizes, int n_in,
                              void* d_out, int out_size, void* d_ws, size_t ws_size,
                              hipStream_t stream) {
    const float* x   = (const float*)d_in[0];
    const float* wgt = (const float*)d_in[1];
    float* out = (float*)d_out;
    float* ws  = (float*)d_ws;

    dim3 grid(Dn / DT, Cn, Bn);   // 4 x 32 x 4 = 512 blocks -> 2/CU resident
    dim3 block(512);

    // 8 steps, ping-pong: in -> ws -> out -> ... -> out
    const float* src = x;
    for (int s = 0; s < 8; s++) {
        float* dst = (s & 1) ? out : ws;
        EmergentSpatialPropagation_step<<<grid, block, 0, stream>>>(src, wgt, dst);
        src = dst;
    }
}